// Round 5
// baseline (191.623 us; speedup 1.0000x reference)
//
#include <hip/hip_runtime.h>
#include <hip/hip_bf16.h>

#define G_ 8
#define GIN_ 256
#define GOUT_ 256
#define NROWS_ 8192
#define LDX_ 2048   // = G_*GIN_ = row stride of x and out

typedef __attribute__((ext_vector_type(4))) float f32x4;
typedef __attribute__((ext_vector_type(8))) short bf16x8;

// ---------------------------------------------------------------------------
// Prep: W [G][GIN=k 256][GOUT=col 256] f32 -> WtB fragment-tiled bf16:
//   granule(g, c, cb, c16, quad) = W[g][k = c*32+quad*8 .. +8][col = cb*16+c16]
//   element offset = g*65536 + (c*16+cb)*512 + c16*32 + quad*8
// A wave's B-frag load (16 cols x 4 quads x 16B) is ONE contiguous 1 KB.
// Grid: 128 blocks (8 g x 4 ktile x 4 coltile) x 256 thr, LDS-tiled.
// (unchanged from R4 — harness-verified)
// ---------------------------------------------------------------------------
__global__ __launch_bounds__(256) void wprep_kernel(const float* __restrict__ W,
                                                    __hip_bfloat16* __restrict__ Wt) {
    __shared__ float tile[64][65];   // +1 pad
    const int bid = blockIdx.x;
    const int g  = bid >> 4;
    const int kt = (bid >> 2) & 3;   // k-tile (64 wide)
    const int ct = bid & 3;          // col-tile (64 wide)
    const float* Wg = W + g * (GIN_ * GOUT_);
    __hip_bfloat16* Wo = Wt + (size_t)g * (GIN_ * GOUT_);
    const int lane_o = threadIdx.x & 63;   // col within tile
    const int sub    = threadIdx.x >> 6;   // 0..3
#pragma unroll
    for (int r = 0; r < 16; ++r) {
        int i = r * 4 + sub;               // k within tile
        tile[i][lane_o] = Wg[(kt * 64 + i) * GOUT_ + ct * 64 + lane_o];
    }
    __syncthreads();
    const int col = threadIdx.x & 63;
    const int kgb = threadIdx.x >> 6;      // 0..3
#pragma unroll
    for (int h = 0; h < 2; ++h) {
        const int kg    = kgb + h * 4;     // 0..7: granule-of-8k in 64-k tile
        const int kglob = kt * 64 + kg * 8;
        const int c     = kglob >> 5;      // k-chunk 0..7
        const int quad  = (kglob >> 3) & 3;
        const int colg  = ct * 64 + col;
        const int cb    = colg >> 4;
        const int c16   = colg & 15;
        union { __hip_bfloat16 hh[8]; bf16x8 v; } cv;
#pragma unroll
        for (int j = 0; j < 8; ++j)
            cv.hh[j] = __float2bfloat16(tile[kg * 8 + j][col]);
        *(bf16x8*)(Wo + (size_t)(c * 16 + cb) * 512 + c16 * 32 + quad * 8) = cv.v;
    }
}

__device__ __forceinline__ bf16x8 cvt8(const f32x4 a, const f32x4 b) {
    union { __hip_bfloat16 h[8]; bf16x8 v; } u;
    u.h[0] = __float2bfloat16(a.x); u.h[1] = __float2bfloat16(a.y);
    u.h[2] = __float2bfloat16(a.z); u.h[3] = __float2bfloat16(a.w);
    u.h[4] = __float2bfloat16(b.x); u.h[5] = __float2bfloat16(b.y);
    u.h[6] = __float2bfloat16(b.z); u.h[7] = __float2bfloat16(b.w);
    return u.v;
}

// ---------------------------------------------------------------------------
// Main fused kernel — NO LDS, NO BARRIER (R5).
//  R0-R4 evidence: three different LDS-staged structures all ~42-60 µs with
//  every pipe <20% busy vs a ~16-21 µs traffic floor. Common mechanism:
//  barrier-separated phases (load burst -> barrier -> compute -> store
//  burst) phase-lock the resident blocks, so HBM alternates between
//  saturated and idle. The x-slab is 16 KB/block = L1/L2-resident, so LDS
//  staging buys nothing (guide Common-mistake #7) — remove it.
//   - Each wave: 16 rows x 32 cols, fully independent. Per K-chunk:
//     A directly from x (lane(lm,q) reads 32 B at row row0+lm, k c*32+q*8;
//     4 lanes/row -> coalesced 128 B row-granules), cvt f32->bf16 in-reg,
//     B-frag (contiguous 1 KB/wave) from L2-hot fragment-tiled Wt.
//   - Depth-1 software pipeline: chunk c+1's A+B issued before chunk c's
//     MFMAs; compiler emits counted vmcnt.
//   - A redundancy x8 (4 in-block waves share rows -> L1; ch-twin block
//     bid^8 -> same-XCD L2). B re-read per row-block -> ~0.5 GB L2, runs
//     parallel with HBM at 34 TB/s.
//   - ~50 live VGPRs -> true 8 waves/SIMD (launch_bounds(256,8)).
// Grid: 8 g x 2 ch x 512 rowblocks = 8192 blocks (~32 queued/CU); bid&7 = g
// keeps Wt[g] XCD-local.
// ---------------------------------------------------------------------------
__global__ __launch_bounds__(256, 8) void gkan_kernel(const float* __restrict__ x,
                                                      const __hip_bfloat16* __restrict__ Wt,
                                                      const float* __restrict__ bias,
                                                      const float* __restrict__ pc,
                                                      const float* __restrict__ qc,
                                                      float* __restrict__ out) {
    const int bid  = blockIdx.x;
    const int g    = bid & 7;
    const int ch   = (bid >> 3) & 1;     // col-half within group
    const int row0 = (bid >> 4) * 16;    // 0..511 row-blocks

    const int t    = threadIdx.x;
    const int wave = t >> 6;             // 0..3
    const int lane = t & 63;
    const int lm   = lane & 15;
    const int q    = lane >> 4;
    const int colbase = ch * 128 + wave * 32;   // within group

    // A: lane (lm,q) owns row row0+lm, k-granule q*8 of each chunk
    const float* ap = x + (size_t)(row0 + lm) * LDX_ + g * GIN_ + q * 8;
    // B: fragment-tiled Wt, colblock = colbase/16, chunk stride 16*512 elems
    const __hip_bfloat16* bp = Wt + (size_t)g * (GIN_ * GOUT_)
                                  + (size_t)(ch * 8 + wave * 2) * 512
                                  + lm * 32 + q * 8;

    // prologue: chunk 0 in flight
    f32x4 ar0 = *(const f32x4*)(ap);
    f32x4 ar1 = *(const f32x4*)(ap + 4);
    bf16x8 cb0 = *(const bf16x8*)(bp);
    bf16x8 cb1 = *(const bf16x8*)(bp + 512);

    f32x4 acc[2] = {};
#pragma unroll
    for (int c = 0; c < 8; ++c) {
        f32x4 nr0, nr1; bf16x8 nb0, nb1;
        if (c < 7) {   // issue chunk c+1 loads before chunk c's MFMAs
            const float* an = ap + (c + 1) * 32;
            nr0 = *(const f32x4*)(an);
            nr1 = *(const f32x4*)(an + 4);
            const __hip_bfloat16* bn = bp + (size_t)(c + 1) * (16 * 512);
            nb0 = *(const bf16x8*)(bn);
            nb1 = *(const bf16x8*)(bn + 512);
        }
        const bf16x8 af = cvt8(ar0, ar1);
        acc[0] = __builtin_amdgcn_mfma_f32_16x16x32_bf16(af, cb0, acc[0], 0, 0, 0);
        acc[1] = __builtin_amdgcn_mfma_f32_16x16x32_bf16(af, cb1, acc[1], 0, 0, 0);
        if (c < 7) { ar0 = nr0; ar1 = nr1; cb0 = nb0; cb1 = nb1; }
    }

    // ---- epilogue consts (loaded after the K-loop; not live in-loop) ----
    const float p0 = pc[g * 4 + 0], p1 = pc[g * 4 + 1];
    const float p2 = pc[g * 4 + 2], p3 = pc[g * 4 + 3];
    const float q0 = qc[g * 3 + 0], q1 = qc[g * 3 + 1], q2 = qc[g * 3 + 2];

    // ---- epilogue: bias + rational, coalesced stores ----
#pragma unroll
    for (int nt = 0; nt < 2; ++nt) {
        const int col = g * GOUT_ + colbase + nt * 16 + lm;
        const float bb = bias[g * GOUT_ + colbase + nt * 16 + lm];
#pragma unroll
        for (int r = 0; r < 4; ++r) {
            const int row_o = row0 + q * 4 + r;
            const float y   = acc[nt][r] + bb;
            const float num = p0 + y * (p1 + y * (p2 + y * p3));
            const float den = 1.0f + fabsf(y * (q0 + y * (q1 + y * q2)));
            out[(size_t)row_o * LDX_ + col] = num * __builtin_amdgcn_rcpf(den);
        }
    }
}

extern "C" void kernel_launch(void* const* d_in, const int* in_sizes, int n_in,
                              void* d_out, int out_size, void* d_ws, size_t ws_size,
                              hipStream_t stream) {
    const float* x = (const float*)d_in[0];
    const float* W = (const float*)d_in[1];
    const float* b = (const float*)d_in[2];
    const float* p = (const float*)d_in[3];
    const float* q = (const float*)d_in[4];
    float* out = (float*)d_out;

    __hip_bfloat16* Wt = (__hip_bfloat16*)d_ws;   // 1 MiB fragment-tiled bf16 W

    wprep_kernel<<<128, 256, 0, stream>>>(W, Wt);
    gkan_kernel<<<8192, 256, 0, stream>>>(x, Wt, b, p, q, out);
}

// Round 6
// 133.779 us; speedup vs baseline: 1.4324x; 1.4324x over previous
//
#include <hip/hip_runtime.h>
#include <hip/hip_bf16.h>

#define G_ 8
#define GIN_ 256
#define GOUT_ 256
#define NROWS_ 8192
#define LDX_ 2048   // = G_*GIN_ = row stride of x and out

typedef __attribute__((ext_vector_type(4))) float f32x4;
typedef __attribute__((ext_vector_type(8))) short bf16x8;

// LDS-only barrier: no vmcnt(0) drain (global ops stay in flight).
__device__ __forceinline__ void lds_barrier() {
    asm volatile("s_waitcnt lgkmcnt(0)\n\ts_barrier" ::: "memory");
}

// ---------------------------------------------------------------------------
// Prep: W [G][GIN=k 256][GOUT=col 256] f32 -> WtB fragment-tiled bf16:
//   granule(g, c, cb, c16, quad) = W[g][k = c*32+quad*8 .. +8][col = cb*16+c16]
//   element offset = g*65536 + (c*16+cb)*512 + c16*32 + quad*8
// A wave's B-frag load (16 cols x 4 quads x 16B) is ONE contiguous 1 KB.
// (unchanged from R4 — harness-verified)
// ---------------------------------------------------------------------------
__global__ __launch_bounds__(256) void wprep_kernel(const float* __restrict__ W,
                                                    __hip_bfloat16* __restrict__ Wt) {
    __shared__ float tile[64][65];   // +1 pad
    const int bid = blockIdx.x;
    const int g  = bid >> 4;
    const int kt = (bid >> 2) & 3;   // k-tile (64 wide)
    const int ct = bid & 3;          // col-tile (64 wide)
    const float* Wg = W + g * (GIN_ * GOUT_);
    __hip_bfloat16* Wo = Wt + (size_t)g * (GIN_ * GOUT_);
    const int lane_o = threadIdx.x & 63;   // col within tile
    const int sub    = threadIdx.x >> 6;   // 0..3
#pragma unroll
    for (int r = 0; r < 16; ++r) {
        int i = r * 4 + sub;               // k within tile
        tile[i][lane_o] = Wg[(kt * 64 + i) * GOUT_ + ct * 64 + lane_o];
    }
    __syncthreads();
    const int col = threadIdx.x & 63;
    const int kgb = threadIdx.x >> 6;      // 0..3
#pragma unroll
    for (int h = 0; h < 2; ++h) {
        const int kg    = kgb + h * 4;     // 0..7: granule-of-8k in 64-k tile
        const int kglob = kt * 64 + kg * 8;
        const int c     = kglob >> 5;      // k-chunk 0..7
        const int quad  = (kglob >> 3) & 3;
        const int colg  = ct * 64 + col;
        const int cb    = colg >> 4;
        const int c16   = colg & 15;
        union { __hip_bfloat16 hh[8]; bf16x8 v; } cv;
#pragma unroll
        for (int j = 0; j < 8; ++j)
            cv.hh[j] = __float2bfloat16(tile[kg * 8 + j][col]);
        *(bf16x8*)(Wo + (size_t)(c * 16 + cb) * 512 + c16 * 32 + quad * 8) = cv.v;
    }
}

// ---------------------------------------------------------------------------
// Main fused kernel — R4 structure + IN-FLIGHT PIPELINE DEPTH (R6).
//  R4's smoking gun: VGPR_Count=24 under launch_bounds(512,8) — the rolled
//  K-loop had NO room to keep loads in flight, so every iteration ate a
//  full L2 round-trip (~300-400cy) vs ~60cy of work. R5 proved occupancy
//  alone is useless (78% occ, 100µs). Fix: keep R4's block/tile/staging/
//  epilogue EXACTLY (clean A/B), but fully unroll the K-loop with
//   - B-prefetch distance 2 (3 pairs live, mod-3 slots, 24 VGPRs)
//   - A ds_read prefetch distance 1 (2 pairs live, 16 VGPRs)
//  and launch_bounds(512,6) so the allocator keeps ~70 regs of pipeline
//  state (6-7 waves/SIMD still resident).
//  B prologue loads issued BEFORE the staging cvt: they ride under the
//  x-load wait (vmcnt counts oldest-N; x issued first).
// Grid: 8 g x 256 rowblocks = 2048 blocks; bid&7 = g keeps Wt[g] XCD-local.
// ---------------------------------------------------------------------------
__global__ __launch_bounds__(512, 6) void gkan_kernel(const float* __restrict__ x,
                                                      const __hip_bfloat16* __restrict__ Wt,
                                                      const float* __restrict__ bias,
                                                      const float* __restrict__ pc,
                                                      const float* __restrict__ qc,
                                                      float* __restrict__ out) {
    __shared__ __align__(16) __hip_bfloat16 As[8192];   // 16 KB: 16 x 1KB chunk-blocks

    const int bid  = blockIdx.x;
    const int g    = bid & 7;
    const int row0 = (bid >> 3) * 32;

    const int t    = threadIdx.x;
    const int wave = t >> 6;             // 0..7 -> cols [wave*32, +32)
    const int lane = t & 63;
    const int lm   = lane & 15;
    const int q    = lane >> 4;

    // ---- x slab loads: thread owns granules su and su+16 of one row ----
    const int row = t >> 4;              // 0..31
    const int su  = t & 15;              // 0..15
    const float* xs = x + (size_t)(row0 + row) * LDX_ + g * GIN_ + su * 8;
    f32x4 a0 = *(const f32x4*)(xs);
    f32x4 a1 = *(const f32x4*)(xs + 4);
    f32x4 b0 = *(const f32x4*)(xs + 128);
    f32x4 b1 = *(const f32x4*)(xs + 132);

    // ---- B prologue: chunks 0,1 issued NOW (ride under the x wait) ----
    const __hip_bfloat16* bp = Wt + (size_t)g * (GIN_ * GOUT_)
                                  + (wave * 2) * 512 + lm * 32 + q * 8;
    bf16x8 B0[3], B1[3];
    B0[0] = *(const bf16x8*)(bp);
    B1[0] = *(const bf16x8*)(bp + 512);
    B0[1] = *(const bf16x8*)(bp + 16 * 512);
    B1[1] = *(const bf16x8*)(bp + 16 * 512 + 512);

    // ---- stage to LDS, chunk-contiguous + XOR slot swizzle ----
    // element addr(granule c,quad of row) = (c*2 + row/16)*512 + (row&15)*32
    //                                       + ((quad ^ (row&3))*8)
    {
        const int rblk = row >> 4, r16 = row & 15, rx = row & 3;
        const int c0 = su >> 2, quad = su & 3;
        const int slot = (quad ^ rx) * 8 + r16 * 32;
        union { __hip_bfloat16 hh[8]; bf16x8 v; } ca, cb;
        ca.hh[0] = __float2bfloat16(a0.x); ca.hh[1] = __float2bfloat16(a0.y);
        ca.hh[2] = __float2bfloat16(a0.z); ca.hh[3] = __float2bfloat16(a0.w);
        ca.hh[4] = __float2bfloat16(a1.x); ca.hh[5] = __float2bfloat16(a1.y);
        ca.hh[6] = __float2bfloat16(a1.z); ca.hh[7] = __float2bfloat16(a1.w);
        cb.hh[0] = __float2bfloat16(b0.x); cb.hh[1] = __float2bfloat16(b0.y);
        cb.hh[2] = __float2bfloat16(b0.z); cb.hh[3] = __float2bfloat16(b0.w);
        cb.hh[4] = __float2bfloat16(b1.x); cb.hh[5] = __float2bfloat16(b1.y);
        cb.hh[6] = __float2bfloat16(b1.z); cb.hh[7] = __float2bfloat16(b1.w);
        *(bf16x8*)(As + (c0 * 2 + rblk) * 512 + slot)       = ca.v;
        *(bf16x8*)(As + ((4 + c0) * 2 + rblk) * 512 + slot) = cb.v;
    }
    lds_barrier();

    // ---- A prologue: chunk 0 fragments from LDS ----
    const __hip_bfloat16* ap = As + lm * 32 + ((q ^ (lm & 3)) * 8);
    bf16x8 A0[2], A1[2];
    A0[0] = *(const bf16x8*)(ap);
    A1[0] = *(const bf16x8*)(ap + 512);

    // ---- K-loop: fully unrolled, B depth-2 + A depth-1 prefetch ----
    f32x4 acc[2][2] = {};
#pragma unroll
    for (int c = 0; c < 8; ++c) {
        if (c < 6) {   // issue B loads for chunk c+2
            const __hip_bfloat16* bn = bp + (size_t)(c + 2) * (16 * 512);
            B0[(c + 2) % 3] = *(const bf16x8*)(bn);
            B1[(c + 2) % 3] = *(const bf16x8*)(bn + 512);
        }
        if (c < 7) {   // issue A ds_reads for chunk c+1
            const __hip_bfloat16* an = ap + (size_t)(c + 1) * (2 * 512);
            A0[(c + 1) & 1] = *(const bf16x8*)(an);
            A1[(c + 1) & 1] = *(const bf16x8*)(an + 512);
        }
        const bf16x8 af0 = A0[c & 1], af1 = A1[c & 1];
        const bf16x8 bf0 = B0[c % 3], bf1 = B1[c % 3];
        acc[0][0] = __builtin_amdgcn_mfma_f32_16x16x32_bf16(af0, bf0, acc[0][0], 0, 0, 0);
        acc[0][1] = __builtin_amdgcn_mfma_f32_16x16x32_bf16(af0, bf1, acc[0][1], 0, 0, 0);
        acc[1][0] = __builtin_amdgcn_mfma_f32_16x16x32_bf16(af1, bf0, acc[1][0], 0, 0, 0);
        acc[1][1] = __builtin_amdgcn_mfma_f32_16x16x32_bf16(af1, bf1, acc[1][1], 0, 0, 0);
    }

    // ---- epilogue consts loaded HERE (not live during the loop) ----
    const float p0 = pc[g * 4 + 0], p1 = pc[g * 4 + 1];
    const float p2 = pc[g * 4 + 2], p3 = pc[g * 4 + 3];
    const float q0 = qc[g * 3 + 0], q1 = qc[g * 3 + 1], q2 = qc[g * 3 + 2];
    float bb[2];
#pragma unroll
    for (int nt = 0; nt < 2; ++nt)
        bb[nt] = bias[g * GOUT_ + wave * 32 + nt * 16 + lm];

    // ---- epilogue: bias + rational, coalesced stores ----
#pragma unroll
    for (int nt = 0; nt < 2; ++nt) {
        const int col = g * GOUT_ + wave * 32 + nt * 16 + lm;
#pragma unroll
        for (int mt = 0; mt < 2; ++mt)
#pragma unroll
            for (int r = 0; r < 4; ++r) {
                const int row_o = row0 + mt * 16 + q * 4 + r;
                const float y   = acc[mt][nt][r] + bb[nt];
                const float num = p0 + y * (p1 + y * (p2 + y * p3));
                const float den = 1.0f + fabsf(y * (q0 + y * (q1 + y * q2)));
                out[(size_t)row_o * LDX_ + col] = num * __builtin_amdgcn_rcpf(den);
            }
    }
}

extern "C" void kernel_launch(void* const* d_in, const int* in_sizes, int n_in,
                              void* d_out, int out_size, void* d_ws, size_t ws_size,
                              hipStream_t stream) {
    const float* x = (const float*)d_in[0];
    const float* W = (const float*)d_in[1];
    const float* b = (const float*)d_in[2];
    const float* p = (const float*)d_in[3];
    const float* q = (const float*)d_in[4];
    float* out = (float*)d_out;

    __hip_bfloat16* Wt = (__hip_bfloat16*)d_ws;   // 1 MiB fragment-tiled bf16 W

    wprep_kernel<<<128, 256, 0, stream>>>(W, Wt);
    gkan_kernel<<<2048, 512, 0, stream>>>(x, Wt, b, p, q, out);
}